// Round 1
// baseline (341.522 us; speedup 1.0000x reference)
//
#include <hip/hip_runtime.h>
#include <cstdint>
#include <cstddef>

// Problem constants (fixed by reference):
#define NSLOTS 16
#define DIM    256        // SLOT_DIM = FEAT_DIM = K = N of both GEMMs
#define FEAT   4096
#define MT     128        // rows per GEMM block tile
#define LDA    264        // Abuf row stride in bf16 elements (+8 pad: 528B rows -> 2-way bank alias, free)

typedef __attribute__((ext_vector_type(8))) short  short8;   // 8 bf16 bit-patterns (4 VGPRs)
typedef __attribute__((ext_vector_type(4))) float  floatx4;  // MFMA accumulator

__device__ __forceinline__ short f2bf(float f) {
    // round-to-nearest-even float -> bf16 bit pattern
    unsigned u = __builtin_bit_cast(unsigned, f);
    u += 0x7FFFu + ((u >> 16) & 1u);
    return (short)(u >> 16);
}

// ---------------------------------------------------------------------------
// Kernel 1: swizzle W1/W2 (fp32 [K=256][N=256] row-major) into bf16 MFMA
// B-fragment order: Ws[((kt*16 + nt)*64 + lane)*8 + j] = W[kt*32 + (lane>>4)*8 + j][nt*16 + (lane&15)]
// so each lane's B fragment for (kt, nt) is one coalesced 16-B load.
// ---------------------------------------------------------------------------
__global__ void swizzle_w_kernel(const float* __restrict__ W1,
                                 const float* __restrict__ W2,
                                 short* __restrict__ W1s,
                                 short* __restrict__ W2s) {
    int t = blockIdx.x * blockDim.x + threadIdx.x;   // 16384 threads total
    int lane = t & 63;
    int nt   = (t >> 6) & 15;
    int kt   = (t >> 10) & 7;
    int m    = t >> 13;
    const float* W  = m ? W2 : W1;
    short*       Ws = m ? W2s : W1s;
    int n  = nt * 16 + (lane & 15);
    int kb = kt * 32 + (lane >> 4) * 8;
    short* dst = Ws + ((size_t)((kt * 16 + nt) * 64 + lane)) * 8;
#pragma unroll
    for (int j = 0; j < 8; ++j)
        dst[j] = f2bf(W[(size_t)(kb + j) * DIM + n]);
}

// ---------------------------------------------------------------------------
// Shared MFMA core: Abuf[128 rows x 256 k] (bf16, stride LDA) times Ws (swizzled
// 256x256 bf16), 512 threads = 8 waves in 2 (m) x 4 (n) arrangement.
// Each wave: 4x4 tiles of 16x16, acc 64 VGPRs.
// ---------------------------------------------------------------------------
__device__ __forceinline__ void mfma_core(const short* Abuf,
                                          const short* __restrict__ Ws,
                                          int tid, floatx4 acc[4][4]) {
    int lane = tid & 63;
    int w    = tid >> 6;
    int m_base = (w >> 2) * 64;
    int ng     = (w & 3) * 4;            // first n-tile index (16-col tiles)
    int arow   = lane & 15;
    int ak     = (lane >> 4) * 8;
#pragma unroll
    for (int kt = 0; kt < 8; ++kt) {
        short8 a[4], b[4];
#pragma unroll
        for (int mt = 0; mt < 4; ++mt)
            a[mt] = *(const short8*)(Abuf + (m_base + mt * 16 + arow) * LDA + kt * 32 + ak);
#pragma unroll
        for (int nt = 0; nt < 4; ++nt)
            b[nt] = *(const short8*)(Ws + ((size_t)((kt * 16 + ng + nt) * 64 + lane)) * 8);
#pragma unroll
        for (int mt = 0; mt < 4; ++mt)
#pragma unroll
            for (int nt = 0; nt < 4; ++nt)
                acc[mt][nt] = __builtin_amdgcn_mfma_f32_16x16x32_bf16(
                    a[mt], b[nt], acc[mt][nt], 0, 0, 0);
    }
}

// ---------------------------------------------------------------------------
// Kernel 2: precompute S1 = slots@W1 + b1 (rows 0..1023) and P1 = pos_embed@W1
// (rows 1024..5119), fp32 output into workspace. 40 blocks x 512 threads.
// ---------------------------------------------------------------------------
__global__ __launch_bounds__(512) void precompute_kernel(
        const float* __restrict__ slots, const float* __restrict__ pos,
        const float* __restrict__ b1, const short* __restrict__ W1s,
        float* __restrict__ S1P1) {
    __shared__ short Abuf[MT * LDA];
    int tid  = threadIdx.x;
    int row0 = blockIdx.x * MT;          // [0, 5120); 1024 % 128 == 0 so a block is all-slots or all-pos
#pragma unroll
    for (int p = 0; p < 8; ++p) {
        int v   = tid + p * 512;         // 0..4095 -> (row, k-octet)
        int row = v >> 5;
        int k0  = (v & 31) * 8;
        int gr  = row0 + row;
        const float* src = (gr < 1024) ? (slots + (size_t)gr * DIM + k0)
                                       : (pos + (size_t)(gr - 1024) * DIM + k0);
        short8 hv;
#pragma unroll
        for (int j = 0; j < 8; ++j) hv[j] = f2bf(src[j]);
        *(short8*)(Abuf + row * LDA + k0) = hv;
    }
    __syncthreads();

    floatx4 acc[4][4];
#pragma unroll
    for (int mt = 0; mt < 4; ++mt)
#pragma unroll
        for (int nt = 0; nt < 4; ++nt)
            acc[mt][nt] = floatx4{0.f, 0.f, 0.f, 0.f};
    mfma_core(Abuf, W1s, tid, acc);

    int lane = tid & 63, w = tid >> 6;
    int m_base = (w >> 2) * 64, n_base = (w & 3) * 64;
    bool isSlots = (row0 < 1024);
#pragma unroll
    for (int nt = 0; nt < 4; ++nt) {
        int col = n_base + nt * 16 + (lane & 15);
        float bias = isSlots ? b1[col] : 0.f;
#pragma unroll
        for (int mt = 0; mt < 4; ++mt) {
            size_t r0 = (size_t)row0 + m_base + mt * 16 + (lane >> 4) * 4;
#pragma unroll
            for (int r = 0; r < 4; ++r)
                S1P1[(r0 + r) * DIM + col] = acc[mt][nt][r] + bias;
        }
    }
}

// ---------------------------------------------------------------------------
// Kernel 3: fused main. Per 128-row tile (one b, 128 consecutive f):
//   argmax over 16 mask values -> h = relu(S1[b,idx] + P1[f]) as bf16 in LDS
//   -> MFMA vs W2 -> +b2 -> store fp32.
// ---------------------------------------------------------------------------
__global__ __launch_bounds__(512) void fused_main_kernel(
        const float* __restrict__ mask, const float* __restrict__ b2,
        const float* __restrict__ S1P1, const short* __restrict__ W2s,
        float* __restrict__ out) {
    __shared__ short Abuf[MT * LDA];
    __shared__ int sIdx[MT];
    int tid  = threadIdx.x;
    int row0 = blockIdx.x * MT;          // global output row = b*4096 + f
    int b    = row0 >> 12;
    int f0   = row0 & (FEAT - 1);

    // argmax over slot axis (first max, matching jnp.argmax)
    if (tid < MT) {
        const float* mp = mask + (size_t)b * NSLOTS * FEAT + (f0 + tid);
        float best = mp[0];
        int bi = 0;
#pragma unroll
        for (int s = 1; s < NSLOTS; ++s) {
            float v = mp[(size_t)s * FEAT];
            if (v > best) { best = v; bi = s; }
        }
        sIdx[tid] = bi;
    }
    __syncthreads();

    // build h tile: relu(S1[b, idx[row]] + P1[f0+row]) -> bf16 into LDS
    const float* P1 = S1P1 + (size_t)1024 * DIM;
#pragma unroll
    for (int p = 0; p < 8; ++p) {
        int v   = tid + p * 512;
        int row = v >> 5;
        int k0  = (v & 31) * 8;
        int s   = sIdx[row];
        const floatx4* s1 = (const floatx4*)(S1P1 + ((size_t)(b * NSLOTS + s)) * DIM + k0);
        const floatx4* p1 = (const floatx4*)(P1 + (size_t)(f0 + row) * DIM + k0);
        floatx4 x0 = s1[0] + p1[0];
        floatx4 x1 = s1[1] + p1[1];
        short8 hv;
#pragma unroll
        for (int j = 0; j < 4; ++j) {
            hv[j]     = f2bf(fmaxf(x0[j], 0.f));
            hv[j + 4] = f2bf(fmaxf(x1[j], 0.f));
        }
        *(short8*)(Abuf + row * LDA + k0) = hv;
    }
    __syncthreads();

    floatx4 acc[4][4];
#pragma unroll
    for (int mt = 0; mt < 4; ++mt)
#pragma unroll
        for (int nt = 0; nt < 4; ++nt)
            acc[mt][nt] = floatx4{0.f, 0.f, 0.f, 0.f};
    mfma_core(Abuf, W2s, tid, acc);

    // epilogue: + b2, store fp32
    int lane = tid & 63, w = tid >> 6;
    int m_base = (w >> 2) * 64, n_base = (w & 3) * 64;
#pragma unroll
    for (int nt = 0; nt < 4; ++nt) {
        int col = n_base + nt * 16 + (lane & 15);
        float bias = b2[col];
#pragma unroll
        for (int mt = 0; mt < 4; ++mt) {
            size_t r0 = (size_t)row0 + m_base + mt * 16 + (lane >> 4) * 4;
            float* op = out + r0 * DIM + col;
#pragma unroll
            for (int r = 0; r < 4; ++r)
                op[(size_t)r * DIM] = acc[mt][nt][r] + bias;
        }
    }
}

// ---------------------------------------------------------------------------
extern "C" void kernel_launch(void* const* d_in, const int* in_sizes, int n_in,
                              void* d_out, int out_size, void* d_ws, size_t ws_size,
                              hipStream_t stream) {
    const float* slots = (const float*)d_in[0];  // [64,16,256]
    const float* mask  = (const float*)d_in[1];  // [64,16,4096]
    const float* pos   = (const float*)d_in[2];  // [1,4096,256]
    const float* W1    = (const float*)d_in[3];  // [256,256]
    const float* b1    = (const float*)d_in[4];  // [256]
    const float* W2    = (const float*)d_in[5];  // [256,256]
    const float* b2    = (const float*)d_in[6];  // [256]
    float* out = (float*)d_out;                  // [64,4096,256] fp32

    // workspace layout: S1P1 fp32 [5120*256] (5 MB) | W1s bf16 [64K] | W2s bf16 [64K]
    char* ws = (char*)d_ws;
    float* S1P1 = (float*)ws;
    short* W1s  = (short*)(ws + (size_t)5120 * 256 * 4);
    short* W2s  = W1s + 65536;

    swizzle_w_kernel<<<64, 256, 0, stream>>>(W1, W2, W1s, W2s);
    precompute_kernel<<<40, 512, 0, stream>>>(slots, pos, b1, W1s, S1P1);
    fused_main_kernel<<<2048, 512, 0, stream>>>(mask, b2, S1P1, W2s, out);
}